// Round 11
// baseline (100.761 us; speedup 1.0000x reference)
//
#include <hip/hip_runtime.h>

// QLinear: y[n,o] = round((sum_k (x[n,k]-xz)*(w[o,k]-wz) + bias[o]) * M + yz)
// N=65536, K=512, OUT=512.
// Exact i8 path: (x-128),(w-128) in [-128,127]; |dot+bias| < 2^24; f32 epilogue exact.
// R11: barrier-free counted-vmcnt K-loop.
//   - tile 32 x 512 (full width): x f32 read exactly once, staged ONCE to LDS i8.
//   - B wave-private: each wave gload_lds's its own 4KB/step dbuf; sync = per-wave
//     s_waitcnt vmcnt(4) only. ZERO s_barrier in the loop, vmcnt never drained.
//   - LDS 80KB -> exactly 2 blocks/CU; bursts of one block overlap loop of other.

#define K_DIM 512
#define OUTF  512
#define NT    8                   // K_DIM / 64
#define B_OFF 16384               // A region: 2 rowgroups x 8 steps x 64 lanes x 16B

typedef __attribute__((ext_vector_type(4))) int   i32x4;
typedef __attribute__((ext_vector_type(4))) float f32x4;

__device__ __forceinline__ void gload16(const void* g, void* l) {
    __builtin_amdgcn_global_load_lds(
        (const __attribute__((address_space(1))) void*)g,
        (__attribute__((address_space(3))) void*)l, 16, 0, 0);
}

// ---------- prepass: weight int32 -> i8 (w - wz), row-major [o][k] ----------
__global__ void wprep(const int* __restrict__ W, unsigned int* __restrict__ Wb,
                      const float* __restrict__ wzp) {
    const int wz = __float2int_rn(wzp[0]);
    int idx = (blockIdx.x * blockDim.x + threadIdx.x) * 4;
    i32x4 w = *reinterpret_cast<const i32x4*>(W + idx);
    unsigned int p = ((unsigned int)(w[0] - wz) & 0xffu)
                   | (((unsigned int)(w[1] - wz) & 0xffu) << 8)
                   | (((unsigned int)(w[2] - wz) & 0xffu) << 16)
                   | (((unsigned int)(w[3] - wz) & 0xffu) << 24);
    Wb[idx >> 2] = p;
}

__device__ __forceinline__ int pack16(const f32x4 v0, const f32x4 v1,
                                      const f32x4 v2, const f32x4 v3,
                                      float xzf, i32x4* out) {
    const f32x4 vv[4] = {v0, v1, v2, v3};
    i32x4 p;
    #pragma unroll
    for (int q = 0; q < 4; ++q) {
        unsigned int u0 = (unsigned int)((int)(vv[q][0] - xzf)) & 0xffu;
        unsigned int u1 = (unsigned int)((int)(vv[q][1] - xzf)) & 0xffu;
        unsigned int u2 = (unsigned int)((int)(vv[q][2] - xzf)) & 0xffu;
        unsigned int u3 = (unsigned int)((int)(vv[q][3] - xzf)) & 0xffu;
        p[q] = (int)(u0 | (u1 << 8) | (u2 << 16) | (u3 << 24));
    }
    *out = p;
    return 0;
}

__global__ __launch_bounds__(512, 4)
void qgemm(const float* __restrict__ X,
           const unsigned char* __restrict__ Wb,
           const int* __restrict__ bias,
           const float* __restrict__ Mp,
           const float* __restrict__ xzp,
           const float* __restrict__ yzp,
           float* __restrict__ Y) {
    // A: [0, 16K)  fragment-major i8, 2 rowgroups x 8 ksteps x 64 lanes x 16B
    // B: [16K, 80K) wave-private dbuf: wave w at 16K + w*8K, 2 x 4 frags x 1KB
    __shared__ unsigned char lds[B_OFF + 8 * 8192];   // 81920 B

    const int tid  = threadIdx.x;
    const int lane = tid & 63;
    const int wid  = tid >> 6;              // 0..7 -> col strip 64*wid
    const int fr   = lane & 15;
    const int fq   = lane >> 4;

    const int row0 = blockIdx.x * 32;       // full-width tile: zero redundancy

    const float xzf = xzp[0];

    // ---------- A stage (once): 64KB f32 -> 16KB i8, fragment-major ----------
    // slot s (0..1023) = frag (g=s>>9, t=(s>>6)&7), lane l=s&63:
    //   row 16g+(l&15), k = 64t + 16*(l>>4). Thread handles slots 2*tid, 2*tid+1
    //   = two ADJACENT rows (r0, r0+1), same k-range (since l0 even).
    {
        const int s0 = tid * 2;
        const int gA = s0 >> 9;
        const int tA = (s0 >> 6) & 7;
        const int l0 = s0 & 63;
        const int r0 = 16 * gA + (l0 & 15);
        const int k0 = 64 * tA + ((l0 >> 4) << 4);
        const float* xa = X + (size_t)(row0 + r0) * K_DIM + k0;
        f32x4 va[4], vb[4];
        #pragma unroll
        for (int q = 0; q < 4; ++q) va[q] = *reinterpret_cast<const f32x4*>(xa + q * 4);
        #pragma unroll
        for (int q = 0; q < 4; ++q) vb[q] = *reinterpret_cast<const f32x4*>(xa + K_DIM + q * 4);
        i32x4 pa, pb;
        pack16(va[0], va[1], va[2], va[3], xzf, &pa);
        pack16(vb[0], vb[1], vb[2], vb[3], xzf, &pb);
        *reinterpret_cast<i32x4*>(&lds[s0 * 16])      = pa;
        *reinterpret_cast<i32x4*>(&lds[s0 * 16 + 16]) = pb;
    }

    // bias folded into accumulator init; wave-tile 32 rows x 64 cols
    i32x4 acc[2][4];
    #pragma unroll
    for (int n = 0; n < 4; ++n) {
        const int bv = bias[wid * 64 + n * 16 + fr];
        acc[0][n] = i32x4{bv, bv, bv, bv};
        acc[1][n] = i32x4{bv, bv, bv, bv};
    }

    __syncthreads();                        // the ONLY barrier

    // ---------- barrier-free K-loop, counted vmcnt ----------
    const unsigned char* wbase = Wb + (size_t)(wid * 64 + fr) * K_DIM + fq * 16;
    const int bBuf = B_OFF + wid * 8192;    // wave-private

    auto gloadB = [&](int t) {
        const unsigned char* g = wbase + t * 64;
        const int d = bBuf + (t & 1) * 4096;
        gload16(g,                &lds[d]);
        gload16(g + 16 * K_DIM,   &lds[d + 1024]);
        gload16(g + 32 * K_DIM,   &lds[d + 2048]);
        gload16(g + 48 * K_DIM,   &lds[d + 3072]);
    };

    gloadB(0);                              // 4 in flight

    #pragma unroll
    for (int t = 0; t < NT; ++t) {
        if (t + 1 < NT) {
            gloadB(t + 1);                  // 8 in flight
            asm volatile("s_waitcnt vmcnt(4)" ::: "memory");   // B[t] ready, B[t+1] flying
        } else {
            asm volatile("s_waitcnt vmcnt(0)" ::: "memory");
        }
        i32x4 af0 = *reinterpret_cast<const i32x4*>(&lds[((0 * 8 + t) * 64 + lane) * 16]);
        i32x4 af1 = *reinterpret_cast<const i32x4*>(&lds[((1 * 8 + t) * 64 + lane) * 16]);
        const int bb = bBuf + (t & 1) * 4096 + lane * 16;
        #pragma unroll
        for (int n = 0; n < 4; ++n) {
            i32x4 bf = *reinterpret_cast<const i32x4*>(&lds[bb + n * 1024]);
            acc[0][n] = __builtin_amdgcn_mfma_i32_16x16x64_i8(af0, bf, acc[0][n], 0, 0, 0);
            acc[1][n] = __builtin_amdgcn_mfma_i32_16x16x64_i8(af1, bf, acc[1][n], 0, 0, 0);
        }
    }

    // ---------- epilogue: y = rintf(acc * M + yz)  (bias pre-folded) ----------
    const float Mv = Mp[0], yz = yzp[0];
    #pragma unroll
    for (int m = 0; m < 2; ++m) {
        const int row = row0 + m * 16 + fq * 4;
        #pragma unroll
        for (int n = 0; n < 4; ++n) {
            float* yp = Y + (size_t)row * OUTF + wid * 64 + n * 16 + fr;
            #pragma unroll
            for (int j = 0; j < 4; ++j)
                yp[(size_t)j * OUTF] = rintf((float)acc[m][n][j] * Mv + yz);
        }
    }
}

extern "C" void kernel_launch(void* const* d_in, const int* in_sizes, int n_in,
                              void* d_out, int out_size, void* d_ws, size_t ws_size,
                              hipStream_t stream) {
    const float* x    = (const float*)d_in[0];
    const int*   w    = (const int*)d_in[1];
    const int*   bias = (const int*)d_in[2];
    const float* M    = (const float*)d_in[3];
    const float* xz   = (const float*)d_in[4];
    const float* wz   = (const float*)d_in[5];
    const float* yz   = (const float*)d_in[6];
    float* y = (float*)d_out;

    unsigned int* Wb = (unsigned int*)d_ws;     // 512*512 i8 = 256 KB

    wprep<<<256, 256, 0, stream>>>(w, Wb, wz);
    qgemm<<<2048, 512, 0, stream>>>(x, (const unsigned char*)Wb, bias, M, xz, yz, y);
}

// Round 12
// 87.515 us; speedup vs baseline: 1.1514x; 1.1514x over previous
//
#include <hip/hip_runtime.h>

// QLinear: y[n,o] = round((sum_k (x[n,k]-xz)*(w[o,k]-wz) + bias[o]) * M + yz)
// N=65536, K=512, OUT=512.
// Exact i8 path: (x-128),(w-128) in [-128,127]; |dot+bias| < 2^24; f32 epilogue exact.
// R12: minimize total cache-system traffic (the measured ~10 TB/s wall).
//   - W col-half (256 cols, 128 KB i8) resident in LDS per block: loaded ONCE.
//   - x streamed in 16-row chunks: reg-staged (dist = 1 chunk) -> i8 -> 8 KB dbuf.
//   - K-loop (8 steps/chunk) is barrier-free: both operands LDS-resident.
//   - ONE barrier per chunk (8/block). Grid 1024 = 512 row-panels x 2 col-halves.

#define K_DIM 512
#define OUTF  512
#define W_LDS  131072            // 128 frags (16 colfrags x 8 ksteps) x 1024 B
#define A_OFF  W_LDS             // A dbuf: 2 x 8192 B (16 rows x 512 K i8, frag-major)

typedef __attribute__((ext_vector_type(4))) int   i32x4;
typedef __attribute__((ext_vector_type(4))) float f32x4;

__device__ __forceinline__ void gload16(const void* g, void* l) {
    __builtin_amdgcn_global_load_lds(
        (const __attribute__((address_space(1))) void*)g,
        (__attribute__((address_space(3))) void*)l, 16, 0, 0);
}

// ---------- prepass: weight int32 -> i8 (w - wz), row-major [o][k] ----------
__global__ void wprep(const int* __restrict__ W, unsigned int* __restrict__ Wb,
                      const float* __restrict__ wzp) {
    const int wz = __float2int_rn(wzp[0]);
    int idx = (blockIdx.x * blockDim.x + threadIdx.x) * 4;
    i32x4 w = *reinterpret_cast<const i32x4*>(W + idx);
    unsigned int p = ((unsigned int)(w[0] - wz) & 0xffu)
                   | (((unsigned int)(w[1] - wz) & 0xffu) << 8)
                   | (((unsigned int)(w[2] - wz) & 0xffu) << 16)
                   | (((unsigned int)(w[3] - wz) & 0xffu) << 24);
    Wb[idx >> 2] = p;
}

__global__ __launch_bounds__(512, 1)
void qgemm(const float* __restrict__ X,
           const unsigned char* __restrict__ Wb,
           const int* __restrict__ bias,
           const float* __restrict__ Mp,
           const float* __restrict__ xzp,
           const float* __restrict__ yzp,
           float* __restrict__ Y) {
    __shared__ unsigned char lds[W_LDS + 2 * 8192];   // 147456 B

    const int tid  = threadIdx.x;
    const int lane = tid & 63;
    const int wid  = tid >> 6;               // 0..7 -> col strip 32*wid of the half
    const int fr   = lane & 15;
    const int fq   = lane >> 4;

    // XCD swizzle (1024 = 8 x 128): within an XCD, col-half alternates fastest so
    // both halves of a row-panel co-reside on one XCD's L2 (2nd x read = L2 hit).
    const int b   = blockIdx.x;
    const int lid = (b & 7) * 128 + (b >> 3);
    const int n0  = (lid & 1) * 256;          // col-half base
    const int row0 = (lid >> 1) * 128;        // 128-row panel

    const float xzf = xzp[0];

    // ---- W-half load (ONCE): wave wid owns col-frags 2wid, 2wid+1 ----
    // frag c, step t at ((c*8+t)*1024); lane l -> W row n0+c*16+(l&15), k t*64+(l>>4)*16.
    {
        const unsigned char* wg = Wb + (size_t)(n0 + wid * 32 + fr) * K_DIM + fq * 16;
        #pragma unroll
        for (int nn = 0; nn < 2; ++nn)
            #pragma unroll
            for (int t = 0; t < 8; ++t)
                gload16(wg + (size_t)nn * 16 * K_DIM + t * 64,
                        &lds[(((2 * wid + nn) * 8 + t) << 10)]);
    }

    // ---- A chunk staging: 16 rows x 512 K. slot s = tid: row (tid&15),
    //      k = 64*(tid>>6) + 16*((tid>>4)&3); thread loads 16 consecutive f32. ----
    const int arow = tid & 15;
    const int ak   = ((tid >> 6) << 6) + (((tid >> 4) & 3) << 4);
    const float* xbase = X + (size_t)(row0 + arow) * K_DIM + ak;
    const int dA = tid * 16;                  // byte offset inside a dbuf

    f32x4 ra[2][4];                           // two chunk staging sets

    auto stageA = [&](int c) {
        const int s = c & 1;
        const float* p = xbase + (size_t)c * 16 * K_DIM;   // chunk c = rows c*16..+15
        #pragma unroll
        for (int q = 0; q < 4; ++q)
            ra[s][q] = *reinterpret_cast<const f32x4*>(p + q * 4);
    };
    auto convwriteA = [&](int c) {
        const int s = c & 1;
        i32x4 pa;
        #pragma unroll
        for (int q = 0; q < 4; ++q) {
            unsigned int u0 = (unsigned int)((int)(ra[s][q][0] - xzf)) & 0xffu;
            unsigned int u1 = (unsigned int)((int)(ra[s][q][1] - xzf)) & 0xffu;
            unsigned int u2 = (unsigned int)((int)(ra[s][q][2] - xzf)) & 0xffu;
            unsigned int u3 = (unsigned int)((int)(ra[s][q][3] - xzf)) & 0xffu;
            pa[q] = (int)(u0 | (u1 << 8) | (u2 << 16) | (u3 << 24));
        }
        *reinterpret_cast<i32x4*>(&lds[A_OFF + s * 8192 + dA]) = pa;
    };

    // bias (constant per block) for this wave's two col-frags
    const int col0 = n0 + wid * 32 + fr;
    const int bv0 = bias[col0];
    const int bv1 = bias[col0 + 16];

    const float Mv = Mp[0], yz = yzp[0];

    // B read offsets for this wave
    const int bOff0 = ((2 * wid)     * 8) << 10;
    const int bOff1 = ((2 * wid + 1) * 8) << 10;

    // prologue: chunk 0 loads -> regs -> dbuf0; W-gloads drain at the barrier
    stageA(0);
    convwriteA(0);
    __syncthreads();

    #pragma unroll
    for (int c = 0; c < 8; ++c) {
        if (c + 1 < 8) stageA(c + 1);         // issue next chunk's loads first

        const int ab = A_OFF + (c & 1) * 8192;
        i32x4 acc0 = {bv0, bv0, bv0, bv0};
        i32x4 acc1 = {bv1, bv1, bv1, bv1};
        #pragma unroll
        for (int t = 0; t < 8; ++t) {
            i32x4 af = *reinterpret_cast<const i32x4*>(&lds[ab + (t << 10) + lane * 16]);
            i32x4 bf0 = *reinterpret_cast<const i32x4*>(&lds[bOff0 + (t << 10) + lane * 16]);
            i32x4 bf1 = *reinterpret_cast<const i32x4*>(&lds[bOff1 + (t << 10) + lane * 16]);
            acc0 = __builtin_amdgcn_mfma_i32_16x16x64_i8(af, bf0, acc0, 0, 0, 0);
            acc1 = __builtin_amdgcn_mfma_i32_16x16x64_i8(af, bf1, acc1, 0, 0, 0);
        }

        // stores for this chunk: rows row0 + c*16 + fq*4 + j
        const int row = row0 + c * 16 + fq * 4;
        float* yp = Y + (size_t)row * OUTF + col0;
        #pragma unroll
        for (int j = 0; j < 4; ++j) {
            yp[(size_t)j * OUTF]      = rintf((float)acc0[j] * Mv + yz);
            yp[(size_t)j * OUTF + 16] = rintf((float)acc1[j] * Mv + yz);
        }

        if (c + 1 < 8) convwriteA(c + 1);     // regs were in flight across compute
        __syncthreads();                      // protect dbuf swap
    }
}

extern "C" void kernel_launch(void* const* d_in, const int* in_sizes, int n_in,
                              void* d_out, int out_size, void* d_ws, size_t ws_size,
                              hipStream_t stream) {
    const float* x    = (const float*)d_in[0];
    const int*   w    = (const int*)d_in[1];
    const int*   bias = (const int*)d_in[2];
    const float* M    = (const float*)d_in[3];
    const float* xz   = (const float*)d_in[4];
    const float* wz   = (const float*)d_in[5];
    const float* yz   = (const float*)d_in[6];
    float* y = (float*)d_out;

    unsigned int* Wb = (unsigned int*)d_ws;     // 512*512 i8 = 256 KB

    wprep<<<256, 256, 0, stream>>>(w, Wb, wz);
    qgemm<<<1024, 512, 0, stream>>>(x, (const unsigned char*)Wb, bias, M, xz, yz, y);
}